// Round 14
// baseline (98.389 us; speedup 1.0000x reference)
//
#include <hip/hip_runtime.h>

#define NB 512
#define NN 50
#define ND 64
#define LOG2E 1.44269504088896340736f

typedef short bf16x8 __attribute__((ext_vector_type(8)));
typedef float f32x4  __attribute__((ext_vector_type(4)));
typedef _Float16 h2  __attribute__((ext_vector_type(2)));
typedef _Float16 h8  __attribute__((ext_vector_type(8)));

// ---- manual LDS arena (bytes) ----  [r13 arena, byte-identical — proven safe.
// r11's region restructure retriggered r8-style scratch spills (~550 MB HBM,
// 4x regression). Counters (FETCH+WRITE >> 10 MB) are the only reliable spill
// detector at the 64-VGPR budget.]
// xa  u16 [64][72]  9216 @ 0     : layer input x / att1 (bf16 MFMA-A rows; pad rows zeroed once)
// wa1t u16[64][72]  9216 @ 9216  : Wa1^T [n][k]
// wa2t u16[64][72]  9216 @ 18432 : Wa2^T [n][k]
// wot  u16[64][72]  9216 @ 27648 : W1^T then W2^T
// kx  f16 [64][120] 15360 @ 36864: per d, records [4p..4p+3] = Ek_2p,Ek_2p+1,ek_2p,ek_2p+1
//                                  (240 B rows: 16B-aligned record pairs -> ds_read_b128)
// xt  f16 [64][56]  7168 @ 52224 : x transposed [d][j] (112 B rows)
// alias xb u16[64][72] 9216 @ 36864 (over kx head; kx dead after ph2, barrier-guarded)
// alias yF f32[50][64] 12800 @ 46080 (over kx tail + xt; both dead in L1 ph3)
#define OFF_XA    0
#define OFF_WA1T  9216
#define OFF_WA2T  18432
#define OFF_WOT   27648
#define OFF_KX    36864
#define OFF_XT    52224
#define OFF_XB    36864
#define OFF_YF    46080
#define SMEM_BYTES 59392
#define KXS 120   // kx row stride, f16 units

__device__ __forceinline__ float bfu(unsigned short u) {
    union { unsigned int i; float f; } v; v.i = ((unsigned int)u) << 16; return v.f;
}
__device__ __forceinline__ unsigned int f2bfbits(float f) {
    union { float f; unsigned int i; } v; v.f = f;
    unsigned int x = v.i;
    return (x + 0x7FFFu + ((x >> 16) & 1u)) >> 16;
}

// One block per batch, 512 threads = 8 waves, 4 blocks/CU (32 waves/CU).
// MFMA 16x16x32_bf16, M padded 50->64, 4x4 tile grid, TWO M-tiles per wave at
// one N-tile: tn = w&3, tm in {2*(w>>2), 2*(w>>2)+1} -> same dcol for both
// tiles, so phase-2 kx/xt loads are shared across all 8 owned rows (2x the
// VALU:DS ratio of the 16-wave version) and ph1/ph3 weight fragments are
// reused across the tile pair. Barriers drain 8 waves with 3 other blocks to
// overlap phase edges. rho stays in VGPRs across the ph1->ph2 barrier.
// w_ij = Eq*max(Ek, rho*ek); Eq cancels in num/den.
// NO unions over vector types (r8); arena untouched (r11).
__global__ __launch_bounds__(512, 8)
void att2_kernel(const float* __restrict__ emb,
                 const float* __restrict__ wa1, const float* __restrict__ ba1,
                 const float* __restrict__ wa2, const float* __restrict__ ba2,
                 const float* __restrict__ w1,  const float* __restrict__ b1,
                 const float* __restrict__ w2,  const float* __restrict__ b2,
                 float* __restrict__ out)
{
    __shared__ __align__(16) unsigned char smem[SMEM_BYTES];
    unsigned short* xa   = (unsigned short*)(smem + OFF_XA);
    unsigned short* wa1t = (unsigned short*)(smem + OFF_WA1T);
    unsigned short* wa2t = (unsigned short*)(smem + OFF_WA2T);
    unsigned short* wot  = (unsigned short*)(smem + OFF_WOT);
    _Float16*       kx   = (_Float16*)(smem + OFF_KX);
    _Float16*       xt   = (_Float16*)(smem + OFF_XT);
    unsigned short* xb   = (unsigned short*)(smem + OFF_XB);   // alias
    float*          yF   = (float*)(smem + OFF_YF);            // alias

    const int b    = blockIdx.x;
    const int tid  = threadIdx.x;
    const int w    = tid >> 6;        // wave 0..7
    const int lane = tid & 63;
    const int ln   = lane & 15;       // MFMA row/col in tile
    const int qd   = lane >> 4;       // MFMA quad
    const int tn   = w & 3;           // N-tile
    const int tm0  = (w >> 2) * 2;    // first M-tile (owns tm0, tm0+1)
    const int dcol = tn * 16 + ln;    // owned column (phases 1,2,3)
    const int i0a  = tm0 * 16 + qd * 4;   // first owned row, tile A
    const int i0b  = i0a + 16;            // first owned row, tile B

    const float* embB = emb + (size_t)b * (NN + 1) * ND;

    // ---- phase 0: stage x (bf16 rows + f16 transposed), zero xa pad, W^T ----
    for (int u = tid; u < (NN * ND) / 2; u += 512) {
        float2 v = *(const float2*)(embB + ND + 2 * u);
        int i = (2 * u) >> 6, c = (2 * u) & 63;
        *(unsigned int*)&xa[i * 72 + c] = (f2bfbits(v.y) << 16) | f2bfbits(v.x);
        xt[c * 56 + i]       = (_Float16)v.x;
        xt[(c + 1) * 56 + i] = (_Float16)v.y;
    }
    for (int u = tid; u < 14 * 72; u += 512) xa[NN * 72 + u] = 0;   // A pad rows
    for (int u = tid; u < ND * ND; u += 512) {
        int k = u >> 6, n = u & 63;
        wa1t[n * 72 + k] = (unsigned short)f2bfbits(wa1[u]);
        wa2t[n * 72 + k] = (unsigned short)f2bfbits(wa2[u]);
        wot [n * 72 + k] = (unsigned short)f2bfbits(w1[u]);
    }
    __syncthreads();

    const float bq = ba1[dcol];
    const float bk = ba2[dcol];

    for (int L = 0; L < 2; ++L) {
        if (L == 1) {   // restage W2^T; last wot read was before the prev barrier
            for (int u = tid; u < ND * ND; u += 512) {
                int k = u >> 6, n = u & 63;
                wot[n * 72 + k] = (unsigned short)f2bfbits(w2[u]);
            }
        }

        // ---- phase 1: q/k GEMM on MFMA (tile pair) + exp epilogue ----
        float rho[8];
        {
            // weight fragments shared by both tiles (depend on dcol/qd only)
            const bf16x8 wq0 = *(const bf16x8*)&wa1t[dcol * 72 + qd * 8];
            const bf16x8 wq1 = *(const bf16x8*)&wa1t[dcol * 72 + 32 + qd * 8];
            const bf16x8 wk0 = *(const bf16x8*)&wa2t[dcol * 72 + qd * 8];
            const bf16x8 wk1 = *(const bf16x8*)&wa2t[dcol * 72 + 32 + qd * 8];
#pragma unroll
            for (int t = 0; t < 2; ++t) {
                const int tmi = tm0 + t;
                const int ib  = tmi * 16 + qd * 4;
                const bf16x8 a0 = *(const bf16x8*)&xa[(tmi * 16 + ln) * 72 + qd * 8];
                const bf16x8 a1 = *(const bf16x8*)&xa[(tmi * 16 + ln) * 72 + 32 + qd * 8];
                f32x4 accq = {bq, bq, bq, bq};
                f32x4 acck = {bk, bk, bk, bk};
                accq = __builtin_amdgcn_mfma_f32_16x16x32_bf16(a0, wq0, accq, 0, 0, 0);
                accq = __builtin_amdgcn_mfma_f32_16x16x32_bf16(a1, wq1, accq, 0, 0, 0);
                acck = __builtin_amdgcn_mfma_f32_16x16x32_bf16(a0, wk0, acck, 0, 0, 0);
                acck = __builtin_amdgcn_mfma_f32_16x16x32_bf16(a1, wk1, acck, 0, 0, 0);

                _Float16 Ekf[4], ekf[4];
#pragma unroll
                for (int reg = 0; reg < 4; ++reg) {
                    rho[4 * t + reg] = __builtin_exp2f(accq[reg] * (-0.99f * LOG2E));
                    float kp = acck[reg] * LOG2E;
                    Ekf[reg] = (_Float16)__builtin_exp2f(kp);
                    ekf[reg] = (_Float16)__builtin_exp2f(0.01f * kp);
                }
                if (ib < NN) {   // rows >= 50 never read in phase 2 (p < 25)
                    h2* kxP = (h2*)(kx + dcol * KXS + ib * 2);   // 16B-aligned
                    kxP[0] = (h2){Ekf[0], Ekf[1]};
                    kxP[1] = (h2){ekf[0], ekf[1]};
                    kxP[2] = (h2){Ekf[2], Ekf[3]};
                    kxP[3] = (h2){ekf[2], ekf[3]};
                }
            }
        }
        __syncthreads();

        // ---- phase 2: packed-f16 softmax-weighted sum, 8 rows, shared loads ----
        float att[8];
        {
            h2 rho2[8], num2[8], den2[8];
#pragma unroll
            for (int r = 0; r < 8; ++r) {
                _Float16 rv = (_Float16)rho[r];
                rho2[r] = (h2){rv, rv};
                num2[r] = (h2)0.f;
                den2[r] = (h2)0.f;
            }
            const _Float16* kxrow = kx + dcol * KXS;
            const h2* xP = (const h2*)(xt + dcol * 56);
            // 12 double-iterations (pairs 0..23) + 1 tail (pair 24)
            for (int q = 0; q < 12; ++q) {
                h8 rec = *(const h8*)(kxrow + 8 * q);      // ds_read_b128: 2 records
                h2 EkA = __builtin_shufflevector(rec, rec, 0, 1);
                h2 ekA = __builtin_shufflevector(rec, rec, 2, 3);
                h2 EkB = __builtin_shufflevector(rec, rec, 4, 5);
                h2 ekB = __builtin_shufflevector(rec, rec, 6, 7);
                h2 xA  = xP[2 * q];
                h2 xB  = xP[2 * q + 1];
#pragma unroll
                for (int r = 0; r < 8; ++r) {
                    h2 wvA = __builtin_elementwise_max(rho2[r] * ekA, EkA);
                    den2[r] = den2[r] + wvA;
                    num2[r] = wvA * xA + num2[r];        // v_pk_fma_f16
                    h2 wvB = __builtin_elementwise_max(rho2[r] * ekB, EkB);
                    den2[r] = den2[r] + wvB;
                    num2[r] = wvB * xB + num2[r];
                }
            }
            {
                const h2* kxP = (const h2*)kxrow;
                h2 Ek2 = kxP[48];                          // pair 24
                h2 ek2 = kxP[49];
                h2 x2  = xP[24];
#pragma unroll
                for (int r = 0; r < 8; ++r) {
                    h2 wv = __builtin_elementwise_max(rho2[r] * ek2, Ek2);
                    den2[r] = den2[r] + wv;
                    num2[r] = wv * x2 + num2[r];
                }
            }
#pragma unroll
            for (int r = 0; r < 8; ++r) {
                float nu = (float)num2[r].x + (float)num2[r].y;
                float de = (float)den2[r].x + (float)den2[r].y;
                att[r] = nu / de;
            }
        }
        __syncthreads();                 // kx fully read -> safe to alias xb
#pragma unroll
        for (int r = 0; r < 8; ++r) {
            const int i = (r < 4 ? i0a : i0b - 4) + r;   // i0a+r | i0b+(r-4)
            if (i < NN)
                xb[i * 72 + dcol] = (unsigned short)f2bfbits(att[r]);
        }
        __syncthreads();

        // ---- phase 3: y = att @ Wl + bl on MFMA (tile pair) ----
        // (xb pad rows hold garbage att: affects only discarded C-rows >= 50)
        {
            const bf16x8 wo0 = *(const bf16x8*)&wot[dcol * 72 + qd * 8];
            const bf16x8 wo1 = *(const bf16x8*)&wot[dcol * 72 + 32 + qd * 8];
            const float bov = (L ? b2 : b1)[dcol];
#pragma unroll
            for (int t = 0; t < 2; ++t) {
                const int tmi = tm0 + t;
                const int ib  = tmi * 16 + qd * 4;
                const bf16x8 c0 = *(const bf16x8*)&xb[(tmi * 16 + ln) * 72 + qd * 8];
                const bf16x8 c1 = *(const bf16x8*)&xb[(tmi * 16 + ln) * 72 + 32 + qd * 8];
                f32x4 y = {bov, bov, bov, bov};
                y = __builtin_amdgcn_mfma_f32_16x16x32_bf16(c0, wo0, y, 0, 0, 0);
                y = __builtin_amdgcn_mfma_f32_16x16x32_bf16(c1, wo1, y, 0, 0, 0);

                if (L == 0) {
                    // att1 -> xa (bf16 rows; pad garbage contained) + xt (guarded)
#pragma unroll
                    for (int reg = 0; reg < 4; ++reg) {
                        const int i = ib + reg;
                        xa[i * 72 + dcol] = (unsigned short)f2bfbits(y[reg]);
                        if (i < NN) xt[dcol * 56 + i] = (_Float16)y[reg];
                    }
                } else {
                    // stage fp32 y over dead kx-tail/xt
#pragma unroll
                    for (int reg = 0; reg < 4; ++reg) {
                        const int i = ib + reg;
                        if (i < NN) yF[i * 64 + dcol] = y[reg];
                    }
                }
            }
            __syncthreads();
            if (L == 1) {
                for (int idx = tid; idx < NN * ND; idx += 512) {
                    const int i  = idx >> 6;
                    const int dd = idx & 63;
                    float e0   = embB[dd];
                    float ie   = embB[ND + idx];
                    float att1 = bfu(xa[i * 72 + dd]);
                    float o    = fmaf(e0, ie, yF[idx] + att1);
                    o = fmaxf(o, 0.01f * o);
                    out[(size_t)b * (NN * ND) + idx] = o;
                }
            }
        }
    }
}

extern "C" void kernel_launch(void* const* d_in, const int* in_sizes, int n_in,
                              void* d_out, int out_size, void* d_ws, size_t ws_size,
                              hipStream_t stream) {
    const float* emb = (const float*)d_in[0];
    const float* wa1 = (const float*)d_in[1];
    const float* ba1 = (const float*)d_in[2];
    const float* wa2 = (const float*)d_in[3];
    const float* ba2 = (const float*)d_in[4];
    const float* w1  = (const float*)d_in[5];
    const float* b1  = (const float*)d_in[6];
    const float* w2  = (const float*)d_in[7];
    const float* b2  = (const float*)d_in[8];
    float* out = (float*)d_out;

    att2_kernel<<<NB, 512, 0, stream>>>(emb, wa1, ba1, wa2, ba2, w1, b1, w2, b2, out);
}

// Round 15
// 95.772 us; speedup vs baseline: 1.0273x; 1.0273x over previous
//
#include <hip/hip_runtime.h>

#define NB 512
#define NN 50
#define ND 64
#define LOG2E 1.44269504088896340736f

typedef short bf16x8 __attribute__((ext_vector_type(8)));
typedef float f32x4  __attribute__((ext_vector_type(4)));
typedef _Float16 h2  __attribute__((ext_vector_type(2)));

// ---- manual LDS arena (bytes) ----  [r10/r12 layout — VERIFIED BEST (95.84 us).
// Probed and rejected: r11 region restructure (scratch spills, 4x regression),
// r13 b128 kx widening (neutral), r14 512-thread/2-tile rebalance (-2.5 us).
// Counters (FETCH+WRITE >> 10 MB) are the only reliable spill detector.]
// xa  u16 [64][72]  9216 @ 0     : layer input x / att1 (bf16 MFMA-A rows; pad rows zeroed once)
// wa1t u16[64][72]  9216 @ 9216  : Wa1^T [n][k]
// wa2t u16[64][72]  9216 @ 18432 : Wa2^T [n][k]
// wot  u16[64][72]  9216 @ 27648 : W1^T then W2^T
// kx  f16 [64][116] 14848 @ 36864: per d, records [4p..4p+3] = Ek_2p,Ek_2p+1,ek_2p,ek_2p+1
//                                  (stride 232 B: 8B-aligned b64 reads, 16 even bank-bases -> conflict-free)
// xt  f16 [64][56]  7168 @ 51712 : x transposed [d][j] (112 B rows, 16B-aligned, 2-way banks = free)
// alias xb u16[64][72] 9216 @ 36864 (over kx head; kx dead after ph2, barrier-guarded)
// alias yF f32[50][64] 12800 @ 46080 (over kx tail + xt; both dead in L1 ph3; disjoint from xb/wot)
#define OFF_XA    0
#define OFF_WA1T  9216
#define OFF_WA2T  18432
#define OFF_WOT   27648
#define OFF_KX    36864
#define OFF_XT    51712
#define OFF_XB    36864
#define OFF_YF    46080
#define SMEM_BYTES 58880

__device__ __forceinline__ float bfu(unsigned short u) {
    union { unsigned int i; float f; } v; v.i = ((unsigned int)u) << 16; return v.f;
}
__device__ __forceinline__ unsigned int f2bfbits(float f) {
    union { float f; unsigned int i; } v; v.f = f;
    unsigned int x = v.i;
    return (x + 0x7FFFu + ((x >> 16) & 1u)) >> 16;
}

// One block per batch, 1024 threads = 16 waves (2 blocks/CU = 32 waves/CU = max).
// MFMA 16x16x32_bf16, M padded 50->64, 4x4 tile grid, 1 tile/wave.
// Phase 2 inherits phase 1's C-fragment ownership: thread (wave w, lane) owns
// rows i0..i0+3 (i0 = tm*16+qd*4) at column dcol = tn*16+ln; rho = exp2(-0.99q')
// stays in VGPRs across the barrier (no qrho LDS round trip). Uniform 4 rows:
// pad rows >= 50 compute finite garbage contained to discarded C-rows.
// w_ij = Eq*max(Ek, rho*ek); Eq cancels in num/den.
// NO unions over vector types (r8: scratch round-trips -> 300 MB HBM, 2.5x).
__global__ __launch_bounds__(1024, 8)
void att2_kernel(const float* __restrict__ emb,
                 const float* __restrict__ wa1, const float* __restrict__ ba1,
                 const float* __restrict__ wa2, const float* __restrict__ ba2,
                 const float* __restrict__ w1,  const float* __restrict__ b1,
                 const float* __restrict__ w2,  const float* __restrict__ b2,
                 float* __restrict__ out)
{
    __shared__ __align__(16) unsigned char smem[SMEM_BYTES];
    unsigned short* xa   = (unsigned short*)(smem + OFF_XA);
    unsigned short* wa1t = (unsigned short*)(smem + OFF_WA1T);
    unsigned short* wa2t = (unsigned short*)(smem + OFF_WA2T);
    unsigned short* wot  = (unsigned short*)(smem + OFF_WOT);
    _Float16*       kx   = (_Float16*)(smem + OFF_KX);
    _Float16*       xt   = (_Float16*)(smem + OFF_XT);
    unsigned short* xb   = (unsigned short*)(smem + OFF_XB);   // alias
    float*          yF   = (float*)(smem + OFF_YF);            // alias

    const int b    = blockIdx.x;
    const int tid  = threadIdx.x;
    const int w    = tid >> 6;        // wave 0..15
    const int lane = tid & 63;
    const int ln   = lane & 15;       // MFMA row/col in tile
    const int qd   = lane >> 4;       // MFMA quad
    const int tm   = w >> 2;          // M-tile
    const int tn   = w & 3;           // N-tile
    const int dcol = tn * 16 + ln;    // owned column (phases 1,2,3)
    const int i0   = tm * 16 + qd * 4;// first owned row

    const float* embB = emb + (size_t)b * (NN + 1) * ND;

    // ---- phase 0: stage x (bf16 rows + f16 transposed), zero xa pad, W^T ----
    for (int u = tid; u < (NN * ND) / 2; u += 1024) {
        float2 v = *(const float2*)(embB + ND + 2 * u);
        int i = (2 * u) >> 6, c = (2 * u) & 63;
        *(unsigned int*)&xa[i * 72 + c] = (f2bfbits(v.y) << 16) | f2bfbits(v.x);
        xt[c * 56 + i]       = (_Float16)v.x;
        xt[(c + 1) * 56 + i] = (_Float16)v.y;
    }
    for (int u = tid; u < 14 * 72; u += 1024) xa[NN * 72 + u] = 0;   // A pad rows
    for (int u = tid; u < ND * ND; u += 1024) {
        int k = u >> 6, n = u & 63;
        wa1t[n * 72 + k] = (unsigned short)f2bfbits(wa1[u]);
        wa2t[n * 72 + k] = (unsigned short)f2bfbits(wa2[u]);
        wot [n * 72 + k] = (unsigned short)f2bfbits(w1[u]);
    }
    __syncthreads();

    const float bq = ba1[dcol];
    const float bk = ba2[dcol];

    for (int L = 0; L < 2; ++L) {
        if (L == 1) {   // restage W2^T; last wot read was before the prev barrier
            for (int u = tid; u < ND * ND; u += 1024) {
                int k = u >> 6, n = u & 63;
                wot[n * 72 + k] = (unsigned short)f2bfbits(w2[u]);
            }
        }

        // ---- phase 1: q/k GEMM on MFMA + exp epilogue (rho stays in regs) ----
        float rho[4];
        {
            const bf16x8 a0 = *(const bf16x8*)&xa[(tm * 16 + ln) * 72 + qd * 8];
            const bf16x8 a1 = *(const bf16x8*)&xa[(tm * 16 + ln) * 72 + 32 + qd * 8];
            f32x4 accq = {bq, bq, bq, bq};
            f32x4 acck = {bk, bk, bk, bk};

            bf16x8 bf_;
            bf_ = *(const bf16x8*)&wa1t[dcol * 72 + qd * 8];
            accq = __builtin_amdgcn_mfma_f32_16x16x32_bf16(a0, bf_, accq, 0, 0, 0);
            bf_ = *(const bf16x8*)&wa1t[dcol * 72 + 32 + qd * 8];
            accq = __builtin_amdgcn_mfma_f32_16x16x32_bf16(a1, bf_, accq, 0, 0, 0);
            bf_ = *(const bf16x8*)&wa2t[dcol * 72 + qd * 8];
            acck = __builtin_amdgcn_mfma_f32_16x16x32_bf16(a0, bf_, acck, 0, 0, 0);
            bf_ = *(const bf16x8*)&wa2t[dcol * 72 + 32 + qd * 8];
            acck = __builtin_amdgcn_mfma_f32_16x16x32_bf16(a1, bf_, acck, 0, 0, 0);

            _Float16 Ekf[4], ekf[4];
#pragma unroll
            for (int reg = 0; reg < 4; ++reg) {
                rho[reg] = __builtin_exp2f(accq[reg] * (-0.99f * LOG2E));
                float kp = acck[reg] * LOG2E;
                Ekf[reg] = (_Float16)__builtin_exp2f(kp);
                ekf[reg] = (_Float16)__builtin_exp2f(0.01f * kp);
            }
            if (i0 < NN) {   // rows >= 50 never read in phase 2 (p < 25)
                h2* kxP = (h2*)(kx + dcol * 116 + i0 * 2);   // 8B-aligned
                kxP[0] = (h2){Ekf[0], Ekf[1]};
                kxP[1] = (h2){ekf[0], ekf[1]};
                kxP[2] = (h2){Ekf[2], Ekf[3]};
                kxP[3] = (h2){ekf[2], ekf[3]};
            }
        }
        __syncthreads();

        // ---- phase 2: packed-f16 softmax-weighted sum, uniform 4 rows ----
        float att[4];
        {
            h2 rho2[4], num2[4], den2[4];
#pragma unroll
            for (int r = 0; r < 4; ++r) {
                _Float16 rv = (_Float16)rho[r];
                rho2[r] = (h2){rv, rv};
                num2[r] = (h2)0.f;
                den2[r] = (h2)0.f;
            }
            const h2* kxP = (const h2*)(kx + dcol * 116);
            const h2* xP  = (const h2*)(xt + dcol * 56);
            for (int p = 0; p < NN / 2; ++p) {
                h2 Ek2 = kxP[2 * p];        // adjacent 8B-aligned -> ds_read_b64
                h2 ek2 = kxP[2 * p + 1];
                h2 x2  = xP[p];
#pragma unroll
                for (int r = 0; r < 4; ++r) {
                    h2 wv = __builtin_elementwise_max(rho2[r] * ek2, Ek2);
                    den2[r] = den2[r] + wv;
                    num2[r] = wv * x2 + num2[r];        // v_pk_fma_f16
                }
            }
#pragma unroll
            for (int r = 0; r < 4; ++r) {
                float nu = (float)num2[r].x + (float)num2[r].y;
                float de = (float)den2[r].x + (float)den2[r].y;
                att[r] = nu / de;
            }
        }
        __syncthreads();                 // kx fully read -> safe to alias xb
#pragma unroll
        for (int reg = 0; reg < 4; ++reg)
            xb[(i0 + reg) * 72 + dcol] = (unsigned short)f2bfbits(att[reg]);
        __syncthreads();

        // ---- phase 3: y = att @ Wl + bl on MFMA ----
        // (xb pad rows hold garbage att: affects only discarded C-rows >= 50)
        {
            const bf16x8 c0 = *(const bf16x8*)&xb[(tm * 16 + ln) * 72 + qd * 8];
            const bf16x8 c1 = *(const bf16x8*)&xb[(tm * 16 + ln) * 72 + 32 + qd * 8];
            const float bov = (L ? b2 : b1)[dcol];
            f32x4 y = {bov, bov, bov, bov};

            bf16x8 bf_;
            bf_ = *(const bf16x8*)&wot[dcol * 72 + qd * 8];
            y = __builtin_amdgcn_mfma_f32_16x16x32_bf16(c0, bf_, y, 0, 0, 0);
            bf_ = *(const bf16x8*)&wot[dcol * 72 + 32 + qd * 8];
            y = __builtin_amdgcn_mfma_f32_16x16x32_bf16(c1, bf_, y, 0, 0, 0);

            if (L == 0) {
                // att1 -> xa (bf16 rows; pad-row garbage contained) + xt (guarded)
#pragma unroll
                for (int reg = 0; reg < 4; ++reg) {
                    const int i = i0 + reg;
                    xa[i * 72 + dcol] = (unsigned short)f2bfbits(y[reg]);
                    if (i < NN) xt[dcol * 56 + i] = (_Float16)y[reg];
                }
                __syncthreads();
            } else {
                // stage fp32 y over dead kx-tail/xt, then coalesced store
#pragma unroll
                for (int reg = 0; reg < 4; ++reg) {
                    const int i = i0 + reg;
                    if (i < NN) yF[i * 64 + dcol] = y[reg];
                }
                __syncthreads();
                for (int idx = tid; idx < NN * ND; idx += 1024) {
                    const int i  = idx >> 6;
                    const int dd = idx & 63;
                    float e0   = embB[dd];
                    float ie   = embB[ND + idx];
                    float att1 = bfu(xa[i * 72 + dd]);
                    float o    = fmaf(e0, ie, yF[idx] + att1);
                    o = fmaxf(o, 0.01f * o);
                    out[(size_t)b * (NN * ND) + idx] = o;
                }
            }
        }
    }
}

extern "C" void kernel_launch(void* const* d_in, const int* in_sizes, int n_in,
                              void* d_out, int out_size, void* d_ws, size_t ws_size,
                              hipStream_t stream) {
    const float* emb = (const float*)d_in[0];
    const float* wa1 = (const float*)d_in[1];
    const float* ba1 = (const float*)d_in[2];
    const float* wa2 = (const float*)d_in[3];
    const float* ba2 = (const float*)d_in[4];
    const float* w1  = (const float*)d_in[5];
    const float* b1  = (const float*)d_in[6];
    const float* w2  = (const float*)d_in[7];
    const float* b2  = (const float*)d_in[8];
    float* out = (float*)d_out;

    att2_kernel<<<NB, 1024, 0, stream>>>(emb, wa1, ba1, wa2, ba2, w1, b1, w2, b2, out);
}